// Round 7
// baseline (190.816 us; speedup 1.0000x reference)
//
#include <hip/hip_runtime.h>
#include <hip/hip_bf16.h>
#include <math.h>

#define SELU_SCALE 1.0507009873554805f
#define SELU_ALPHA 1.6732632423543772f

static constexpr int B_ = 16, T_ = 16, L_ = 512, H_ = 768;

typedef __bf16 bf16x8 __attribute__((ext_vector_type(8)));
typedef __bf16 bf16x4 __attribute__((ext_vector_type(4)));
typedef float  f32x4  __attribute__((ext_vector_type(4)));

__device__ __forceinline__ float bf_lo(unsigned u) { return __uint_as_float(u << 16); }
__device__ __forceinline__ float bf_hi(unsigned u) { return __uint_as_float(u & 0xFFFF0000u); }

__device__ __forceinline__ float selu_core(float x) {
    float e = fmaf(__expf(x), SELU_ALPHA, -SELU_ALPHA);
    return x > 0.0f ? x : e;
}

__device__ __forceinline__ bf16x4 cvt4(float4 f) {
    bf16x4 o;
    o.x = (__bf16)f.x; o.y = (__bf16)f.y; o.z = (__bf16)f.z; o.w = (__bf16)f.w;
    return o;
}

// LDS k-segment slot swizzle: slot = seg ^ ((row>>1)&3) -- conflict-free for all
// ds_write_b128 / ds_read_b128 patterns in gemm_k (8-lane phase enumeration).
__device__ __forceinline__ int xsw(int r) { return (r >> 1) & 3; }

// ---------------- prep: W1/W2 -> bf16, dj gather (f32), zero out ----------------
__global__ __launch_bounds__(256) void prep_k(
        const float* __restrict__ w1, const float* __restrict__ w2,
        const float* __restrict__ dec, const int* __restrict__ Yi,
        __bf16* __restrict__ w1b, __bf16* __restrict__ w2b,
        float* __restrict__ djf, float* __restrict__ out) {
    const int NW = H_ * H_ / 4;                // 147456 float4s
    int i = blockIdx.x * 256 + threadIdx.x;
    if (i == 0) out[0] = 0.0f;
    if (i < NW) {
        ((bf16x4*)w1b)[i] = cvt4(((const float4*)w1)[i]);
    } else if (i < 2 * NW) {
        int j = i - NW;
        ((bf16x4*)w2b)[j] = cvt4(((const float4*)w2)[j]);
    } else {
        int j = i - 2 * NW;                    // < 49152
        int bt = j / 192, c = j % 192;
        int b = bt >> 4;
        int y = Yi[bt];
        ((float4*)djf)[bt * 192 + c] = ((const float4*)dec)[(b * L_ + y) * 192 + c];
    }
}

// ---------------- register-pipelined NT GEMM (WE + WD) --------------------------
// C[m][n] = sum_k A[m][k]*B[n][k]. A f32 (convert in-register), B bf16.
// BM=64, BN=128, BK=32, 4 waves (2x2) of 32x64. XCD-aware mapping: same-m
// blocks at block-index stride 128 (== 0 mod 8) -> same XCD L2 -> A fetched
// once per XCD. Prefetch distance 2 (ping-pong regs) across raw s_barriers.
__global__ __launch_bounds__(256) void gemm_k(
        const float* __restrict__ hn, const float* __restrict__ djf,
        const __bf16* __restrict__ w1b, const __bf16* __restrict__ w2b,
        __bf16* __restrict__ web, __bf16* __restrict__ wdb) {
    __shared__ __bf16 As[64 * 32];    // 4 KB
    __shared__ __bf16 Bs[128 * 32];   // 8 KB

    int bx = blockIdx.x;
    const float* Af; const __bf16* Bw; __bf16* C; int m0, n0;
    if (bx < 768) {                       // WE: 128 m-tiles x 6 n-chunks
        Af = hn;  Bw = w1b; C = web;
        m0 = (bx & 127) * 64; n0 = (bx >> 7) * 128;
    } else {                              // WD: 4 m-tiles x 6 n-chunks
        bx -= 768;
        Af = djf; Bw = w2b; C = wdb;
        m0 = (bx & 3) * 64;   n0 = (bx >> 2) * 128;
    }

    const int tid = threadIdx.x;
    const int wave = tid >> 6, lane = tid & 63;
    const int wm = (wave >> 1) * 32, wn = (wave & 1) * 64;
    const int lr = lane & 15, q = lane >> 4;

    // A staging: thread -> row tid>>2, k-seg tid&3 (8 f32 -> 8 bf16 = 1 b128)
    const int arow = tid >> 2, aseg = tid & 3;
    const float* Ag = Af + (size_t)(m0 + arow) * 768 + aseg * 8;
    bf16x8* AsW = (bf16x8*)&As[arow * 32 + ((aseg ^ xsw(arow)) * 8)];

    // B staging: thread -> row tid>>1, k-segs (tid&1)*2, +1 (2 x b128)
    const int brow = tid >> 1, bs0 = (tid & 1) * 2;
    const __bf16* Bg = Bw + (size_t)(n0 + brow) * 768 + bs0 * 8;
    uint4* BsW0 = (uint4*)&Bs[brow * 32 + (((bs0)     ^ xsw(brow)) * 8)];
    uint4* BsW1 = (uint4*)&Bs[brow * 32 + (((bs0 + 1) ^ xsw(brow)) * 8)];

    // fragment read offsets (seg q of row)
    int aoff[2], boff[4];
#pragma unroll
    for (int i = 0; i < 2; ++i) {
        int r = wm + i * 16 + lr;
        aoff[i] = r * 32 + (q ^ xsw(r)) * 8;
    }
#pragma unroll
    for (int j = 0; j < 4; ++j) {
        int r = wn + j * 16 + lr;
        boff[j] = r * 32 + (q ^ xsw(r)) * 8;
    }

    f32x4 acc[2][4] = {};

    // prologue: prefetch tiles 0 and 1 (ping-pong register sets)
    float4 pa0[2], pa1[2]; uint4 pb0[2], pb1[2];
    pa0[0] = *(const float4*)(Ag);      pa1[0] = *(const float4*)(Ag + 4);
    pb0[0] = *(const uint4*)(Bg);       pb1[0] = *(const uint4*)(Bg + 8);
    pa0[1] = *(const float4*)(Ag + 32); pa1[1] = *(const float4*)(Ag + 36);
    pb0[1] = *(const uint4*)(Bg + 32);  pb1[1] = *(const uint4*)(Bg + 40);

    for (int k0 = 0; k0 < 768; k0 += 32) {
        const int s = (k0 >> 5) & 1;
        // stage register set s -> LDS
        bf16x8 aw;
        aw[0] = (__bf16)pa0[s].x; aw[1] = (__bf16)pa0[s].y;
        aw[2] = (__bf16)pa0[s].z; aw[3] = (__bf16)pa0[s].w;
        aw[4] = (__bf16)pa1[s].x; aw[5] = (__bf16)pa1[s].y;
        aw[6] = (__bf16)pa1[s].z; aw[7] = (__bf16)pa1[s].w;
        *AsW  = aw;
        *BsW0 = pb0[s];
        *BsW1 = pb1[s];
        asm volatile("s_waitcnt lgkmcnt(0)\n\ts_barrier" ::: "memory");

        // prefetch tile k+2 into set s -- stays in flight ~2 iterations
        if (k0 + 64 < 768) {
            pa0[s] = *(const float4*)(Ag + k0 + 64);
            pa1[s] = *(const float4*)(Ag + k0 + 68);
            pb0[s] = *(const uint4*)(Bg + k0 + 64);
            pb1[s] = *(const uint4*)(Bg + k0 + 72);
        }

        bf16x8 af[2], bfr[4];
#pragma unroll
        for (int i = 0; i < 2; ++i) af[i]  = *(const bf16x8*)&As[aoff[i]];
#pragma unroll
        for (int j = 0; j < 4; ++j) bfr[j] = *(const bf16x8*)&Bs[boff[j]];
#pragma unroll
        for (int i = 0; i < 2; ++i)
#pragma unroll
            for (int j = 0; j < 4; ++j)
                acc[i][j] = __builtin_amdgcn_mfma_f32_16x16x32_bf16(af[i], bfr[j], acc[i][j], 0, 0, 0);
        asm volatile("s_barrier" ::: "memory");
    }

#pragma unroll
    for (int i = 0; i < 2; ++i)
#pragma unroll
        for (int j = 0; j < 4; ++j)
#pragma unroll
            for (int r = 0; r < 4; ++r) {
                int row = m0 + wm + i * 16 + q * 4 + r;
                int col = n0 + wn + j * 16 + lr;
                C[(size_t)row * 768 + col] = (__bf16)acc[i][j][r];
            }
}

// ---------------- fused scores: per-lane (t,l), no shuffles ----------------
__global__ __launch_bounds__(256) void scores_k(
        const __bf16* __restrict__ web, const __bf16* __restrict__ wdb,
        const float* __restrict__ V, const int* __restrict__ Xi,
        float* __restrict__ scores) {
    __shared__ float    we_s[16][772];
    __shared__ unsigned wd_s[16][388];
    __shared__ float    v_s[768];

    const int b = blockIdx.x, l0 = blockIdx.y * 16;

    for (int c = threadIdx.x; c < 16 * 96; c += 256) {
        int r = c / 96, cc = c % 96;
        uint4 v = *(const uint4*)(web + ((size_t)(b * L_ + l0 + r)) * H_ + cc * 8);
        float4 f0, f1;
        f0.x = bf_lo(v.x); f0.y = bf_hi(v.x); f0.z = bf_lo(v.y); f0.w = bf_hi(v.y);
        f1.x = bf_lo(v.z); f1.y = bf_hi(v.z); f1.z = bf_lo(v.w); f1.w = bf_hi(v.w);
        *(float4*)&we_s[r][cc * 8]     = f0;
        *(float4*)&we_s[r][cc * 8 + 4] = f1;
    }
    for (int c = threadIdx.x; c < 16 * 96; c += 256) {
        int r = c / 96, cc = c % 96;
        *(uint4*)&wd_s[r][cc * 4] = *(const uint4*)(wdb + ((size_t)(b * T_ + r)) * H_ + cc * 8);
    }
    if (threadIdx.x < 192) *(float4*)&v_s[threadIdx.x * 4] = ((const float4*)V)[threadIdx.x];
    __syncthreads();

    const int t = threadIdx.x >> 4;
    const int ls = threadIdx.x & 15;
    const int l = l0 + ls;
    const int X = Xi[b * T_ + t];
    if (!__any(l >= X)) return;

    float a0 = 0.f, a1 = 0.f, a2 = 0.f, a3 = 0.f;
#pragma unroll 4
    for (int h = 0; h < H_; h += 8) {
        float4 w0 = *(const float4*)&we_s[ls][h];
        float4 w1 = *(const float4*)&we_s[ls][h + 4];
        uint4  wd = *(const uint4*)&wd_s[t][h >> 1];
        float4 v0 = *(const float4*)&v_s[h];
        float4 v1 = *(const float4*)&v_s[h + 4];
        a0 = fmaf(selu_core(w0.x + bf_lo(wd.x)), v0.x, a0);
        a1 = fmaf(selu_core(w0.y + bf_hi(wd.x)), v0.y, a1);
        a2 = fmaf(selu_core(w0.z + bf_lo(wd.y)), v0.z, a2);
        a3 = fmaf(selu_core(w0.w + bf_hi(wd.y)), v0.w, a3);
        a0 = fmaf(selu_core(w1.x + bf_lo(wd.z)), v1.x, a0);
        a1 = fmaf(selu_core(w1.y + bf_hi(wd.z)), v1.y, a1);
        a2 = fmaf(selu_core(w1.z + bf_lo(wd.w)), v1.z, a2);
        a3 = fmaf(selu_core(w1.w + bf_hi(wd.w)), v1.w, a3);
    }
    float dot = SELU_SCALE * ((a0 + a1) + (a2 + a3));
    float sc  = dot > 0.0f ? SELU_SCALE * dot
                           : SELU_SCALE * SELU_ALPHA * (__expf(dot) - 1.0f);
    scores[((size_t)(b * T_ + t)) * L_ + l] = sc;
}

// ---------------- per-(b,t) masked logsumexp + gold + mean (atomic) -------------
__global__ __launch_bounds__(64) void loss_k(
        const float* __restrict__ scores, const int* __restrict__ Xi,
        const int* __restrict__ Yi, float* __restrict__ out) {
    const int bt = blockIdx.x;
    const int lane = threadIdx.x;
    const int X = Xi[bt];
    const int Y = Yi[bt];
    const float* row = scores + (size_t)bt * L_;

    float m = -INFINITY;
    for (int l = X + lane; l < L_; l += 64) m = fmaxf(m, row[l]);
#pragma unroll
    for (int off = 32; off > 0; off >>= 1) m = fmaxf(m, __shfl_xor(m, off));

    float s = 0.0f;
    for (int l = X + lane; l < L_; l += 64) s += __expf(row[l] - m);
#pragma unroll
    for (int off = 32; off > 0; off >>= 1) s += __shfl_xor(s, off);

    if (lane == 0)
        atomicAdd(out, (m + __logf(s) - row[Y]) * (1.0f / (B_ * T_)));
}

// ---------------- launch ----------------
extern "C" void kernel_launch(void* const* d_in, const int* in_sizes, int n_in,
                              void* d_out, int out_size, void* d_ws, size_t ws_size,
                              hipStream_t stream) {
    const float* hn  = (const float*)d_in[0];
    const float* dec = (const float*)d_in[1];
    const float* W1  = (const float*)d_in[2];
    const float* W2  = (const float*)d_in[3];
    const float* V   = (const float*)d_in[4];
    const int*   Xi  = (const int*)d_in[5];
    const int*   Yi  = (const int*)d_in[6];
    float* out = (float*)d_out;

    char* ws = (char*)d_ws;
    size_t off = 0;
    auto alloc = [&](size_t bytes) -> char* {
        char* p = ws + off;
        off += (bytes + 255) & ~(size_t)255;
        return p;
    };
    __bf16* w1b    = (__bf16*)alloc((size_t)H_ * H_ * 2);
    __bf16* w2b    = (__bf16*)alloc((size_t)H_ * H_ * 2);
    float*  djf    = (float*)alloc((size_t)B_ * T_ * H_ * 4);
    __bf16* web    = (__bf16*)alloc((size_t)B_ * L_ * H_ * 2);
    __bf16* wdb    = (__bf16*)alloc((size_t)B_ * T_ * H_ * 2);
    float*  scores = (float*)alloc((size_t)B_ * T_ * L_ * 4);

    // prep: (2*147456 + 49152) / 256 = 1344 blocks
    prep_k<<<1344, 256, 0, stream>>>(W1, W2, dec, Yi, w1b, w2b, djf, out);
    // WE (768 blocks, XCD-swizzled) + WD (24 blocks), prefetch-2 pipeline
    gemm_k<<<792, 256, 0, stream>>>(hn, djf, w1b, w2b, web, wdb);
    scores_k<<<dim3(B_, L_ / 16), 256, 0, stream>>>(web, wdb, V, Xi, scores);
    loss_k<<<B_ * T_, 64, 0, stream>>>(scores, Xi, Yi, out);
}

// Round 8
// 158.643 us; speedup vs baseline: 1.2028x; 1.2028x over previous
//
#include <hip/hip_runtime.h>
#include <hip/hip_bf16.h>
#include <math.h>

#define SELU_SCALE 1.0507009873554805f
#define SELU_ALPHA 1.6732632423543772f

static constexpr int B_ = 16, T_ = 16, L_ = 512, H_ = 768;

typedef __bf16 bf16x8 __attribute__((ext_vector_type(8)));
typedef __bf16 bf16x4 __attribute__((ext_vector_type(4)));
typedef float  f32x4  __attribute__((ext_vector_type(4)));

__device__ __forceinline__ float bf_lo(unsigned u) { return __uint_as_float(u << 16); }
__device__ __forceinline__ float bf_hi(unsigned u) { return __uint_as_float(u & 0xFFFF0000u); }

__device__ __forceinline__ float selu_core(float x) {
    float e = fmaf(__expf(x), SELU_ALPHA, -SELU_ALPHA);
    return x > 0.0f ? x : e;
}

__device__ __forceinline__ bf16x4 cvt4(float4 f) {
    bf16x4 o;
    o.x = (__bf16)f.x; o.y = (__bf16)f.y; o.z = (__bf16)f.z; o.w = (__bf16)f.w;
    return o;
}

// LDS k-segment slot swizzle: slot = seg ^ ((row>>1)&3) -- conflict-free for all
// ds_write_b128 / ds_read_b128 patterns in gemm_k (8-lane phase enumeration).
__device__ __forceinline__ int xsw(int r) { return (r >> 1) & 3; }

// ---------------- prep: W1/W2 -> bf16, dj gather (f32), zero out ----------------
__global__ __launch_bounds__(256) void prep_k(
        const float* __restrict__ w1, const float* __restrict__ w2,
        const float* __restrict__ dec, const int* __restrict__ Yi,
        __bf16* __restrict__ w1b, __bf16* __restrict__ w2b,
        float* __restrict__ djf, float* __restrict__ out) {
    const int NW = H_ * H_ / 4;                // 147456 float4s
    int i = blockIdx.x * 256 + threadIdx.x;
    if (i == 0) out[0] = 0.0f;
    if (i < NW) {
        ((bf16x4*)w1b)[i] = cvt4(((const float4*)w1)[i]);
    } else if (i < 2 * NW) {
        int j = i - NW;
        ((bf16x4*)w2b)[j] = cvt4(((const float4*)w2)[j]);
    } else {
        int j = i - 2 * NW;                    // < 49152
        int bt = j / 192, c = j % 192;
        int b = bt >> 4;
        int y = Yi[bt];
        ((float4*)djf)[bt * 192 + c] = ((const float4*)dec)[(b * L_ + y) * 192 + c];
    }
}

// ---------------- register-pipelined NT GEMM (WE + WD) --------------------------
// C[m][n] = sum_k A[m][k]*B[n][k]. A f32 (convert in-register), B bf16.
// BM=64, BN=128, BK=32, 4 waves (2x2) of 32x64. XCD-aware mapping (same-m
// blocks at stride 128 == 0 mod 8 -> same XCD L2). Prefetch distance 2 with
// STATICALLY NAMED ping/pong register sets (k-loop unrolled x2) -- dynamic
// indexing of the prefetch arrays caused LDS-promotion + scratch spills in r7.
__global__ __launch_bounds__(256) void gemm_k(
        const float* __restrict__ hn, const float* __restrict__ djf,
        const __bf16* __restrict__ w1b, const __bf16* __restrict__ w2b,
        __bf16* __restrict__ web, __bf16* __restrict__ wdb) {
    __shared__ __bf16 As[64 * 32];    // 4 KB
    __shared__ __bf16 Bs[128 * 32];   // 8 KB

    int bx = blockIdx.x;
    const float* Af; const __bf16* Bw; __bf16* C; int m0, n0;
    if (bx < 768) {                       // WE: 128 m-tiles x 6 n-chunks
        Af = hn;  Bw = w1b; C = web;
        m0 = (bx & 127) * 64; n0 = (bx >> 7) * 128;
    } else {                              // WD: 4 m-tiles x 6 n-chunks
        bx -= 768;
        Af = djf; Bw = w2b; C = wdb;
        m0 = (bx & 3) * 64;   n0 = (bx >> 2) * 128;
    }

    const int tid = threadIdx.x;
    const int wave = tid >> 6, lane = tid & 63;
    const int wm = (wave >> 1) * 32, wn = (wave & 1) * 64;
    const int lr = lane & 15, q = lane >> 4;

    // A staging: thread -> row tid>>2, k-seg tid&3 (8 f32 -> 8 bf16 = 1 b128)
    const int arow = tid >> 2, aseg = tid & 3;
    const float* Ag = Af + (size_t)(m0 + arow) * 768 + aseg * 8;
    bf16x8* AsW = (bf16x8*)&As[arow * 32 + ((aseg ^ xsw(arow)) * 8)];

    // B staging: thread -> row tid>>1, k-segs (tid&1)*2, +1 (2 x b128)
    const int brow = tid >> 1, bs0 = (tid & 1) * 2;
    const __bf16* Bg = Bw + (size_t)(n0 + brow) * 768 + bs0 * 8;
    uint4* BsW0 = (uint4*)&Bs[brow * 32 + (((bs0)     ^ xsw(brow)) * 8)];
    uint4* BsW1 = (uint4*)&Bs[brow * 32 + (((bs0 + 1) ^ xsw(brow)) * 8)];

    // fragment read offsets (seg q of row)
    int aoff[2], boff[4];
#pragma unroll
    for (int i = 0; i < 2; ++i) {
        int r = wm + i * 16 + lr;
        aoff[i] = r * 32 + (q ^ xsw(r)) * 8;
    }
#pragma unroll
    for (int j = 0; j < 4; ++j) {
        int r = wn + j * 16 + lr;
        boff[j] = r * 32 + (q ^ xsw(r)) * 8;
    }

    f32x4 acc[2][4] = {};

    // prologue: tile 0 -> set X, tile 1 -> set Y (all statically named)
    float4 pax0 = *(const float4*)(Ag);      float4 pax1 = *(const float4*)(Ag + 4);
    uint4  pbx0 = *(const uint4*)(Bg);       uint4  pbx1 = *(const uint4*)(Bg + 8);
    float4 pay0 = *(const float4*)(Ag + 32); float4 pay1 = *(const float4*)(Ag + 36);
    uint4  pby0 = *(const uint4*)(Bg + 32);  uint4  pby1 = *(const uint4*)(Bg + 40);

#pragma unroll 1
    for (int k0 = 0; k0 < 768; k0 += 64) {
        // ======== sub-iter X: tile k0 ========
        {
            bf16x8 aw;
            aw[0] = (__bf16)pax0.x; aw[1] = (__bf16)pax0.y;
            aw[2] = (__bf16)pax0.z; aw[3] = (__bf16)pax0.w;
            aw[4] = (__bf16)pax1.x; aw[5] = (__bf16)pax1.y;
            aw[6] = (__bf16)pax1.z; aw[7] = (__bf16)pax1.w;
            *AsW  = aw;
            *BsW0 = pbx0;
            *BsW1 = pbx1;
            asm volatile("s_waitcnt lgkmcnt(0)\n\ts_barrier" ::: "memory");
            if (k0 + 64 < 768) {   // prefetch tile k0+64 into set X
                pax0 = *(const float4*)(Ag + k0 + 64);
                pax1 = *(const float4*)(Ag + k0 + 68);
                pbx0 = *(const uint4*)(Bg + k0 + 64);
                pbx1 = *(const uint4*)(Bg + k0 + 72);
            }
            bf16x8 af[2], bfr[4];
#pragma unroll
            for (int i = 0; i < 2; ++i) af[i]  = *(const bf16x8*)&As[aoff[i]];
#pragma unroll
            for (int j = 0; j < 4; ++j) bfr[j] = *(const bf16x8*)&Bs[boff[j]];
#pragma unroll
            for (int i = 0; i < 2; ++i)
#pragma unroll
                for (int j = 0; j < 4; ++j)
                    acc[i][j] = __builtin_amdgcn_mfma_f32_16x16x32_bf16(af[i], bfr[j], acc[i][j], 0, 0, 0);
            asm volatile("s_barrier" ::: "memory");
        }
        // ======== sub-iter Y: tile k0+32 ========
        {
            bf16x8 aw;
            aw[0] = (__bf16)pay0.x; aw[1] = (__bf16)pay0.y;
            aw[2] = (__bf16)pay0.z; aw[3] = (__bf16)pay0.w;
            aw[4] = (__bf16)pay1.x; aw[5] = (__bf16)pay1.y;
            aw[6] = (__bf16)pay1.z; aw[7] = (__bf16)pay1.w;
            *AsW  = aw;
            *BsW0 = pby0;
            *BsW1 = pby1;
            asm volatile("s_waitcnt lgkmcnt(0)\n\ts_barrier" ::: "memory");
            if (k0 + 96 < 768) {   // prefetch tile k0+96 into set Y
                pay0 = *(const float4*)(Ag + k0 + 96);
                pay1 = *(const float4*)(Ag + k0 + 100);
                pby0 = *(const uint4*)(Bg + k0 + 96);
                pby1 = *(const uint4*)(Bg + k0 + 104);
            }
            bf16x8 af[2], bfr[4];
#pragma unroll
            for (int i = 0; i < 2; ++i) af[i]  = *(const bf16x8*)&As[aoff[i]];
#pragma unroll
            for (int j = 0; j < 4; ++j) bfr[j] = *(const bf16x8*)&Bs[boff[j]];
#pragma unroll
            for (int i = 0; i < 2; ++i)
#pragma unroll
                for (int j = 0; j < 4; ++j)
                    acc[i][j] = __builtin_amdgcn_mfma_f32_16x16x32_bf16(af[i], bfr[j], acc[i][j], 0, 0, 0);
            asm volatile("s_barrier" ::: "memory");
        }
    }

#pragma unroll
    for (int i = 0; i < 2; ++i)
#pragma unroll
        for (int j = 0; j < 4; ++j)
#pragma unroll
            for (int r = 0; r < 4; ++r) {
                int row = m0 + wm + i * 16 + q * 4 + r;
                int col = n0 + wn + j * 16 + lr;
                C[(size_t)row * 768 + col] = (__bf16)acc[i][j][r];
            }
}

// ---------------- fused scores: per-lane (t,l), no shuffles ----------------
__global__ __launch_bounds__(256) void scores_k(
        const __bf16* __restrict__ web, const __bf16* __restrict__ wdb,
        const float* __restrict__ V, const int* __restrict__ Xi,
        float* __restrict__ scores) {
    __shared__ float    we_s[16][772];
    __shared__ unsigned wd_s[16][388];
    __shared__ float    v_s[768];

    const int b = blockIdx.x, l0 = blockIdx.y * 16;

    for (int c = threadIdx.x; c < 16 * 96; c += 256) {
        int r = c / 96, cc = c % 96;
        uint4 v = *(const uint4*)(web + ((size_t)(b * L_ + l0 + r)) * H_ + cc * 8);
        float4 f0, f1;
        f0.x = bf_lo(v.x); f0.y = bf_hi(v.x); f0.z = bf_lo(v.y); f0.w = bf_hi(v.y);
        f1.x = bf_lo(v.z); f1.y = bf_hi(v.z); f1.z = bf_lo(v.w); f1.w = bf_hi(v.w);
        *(float4*)&we_s[r][cc * 8]     = f0;
        *(float4*)&we_s[r][cc * 8 + 4] = f1;
    }
    for (int c = threadIdx.x; c < 16 * 96; c += 256) {
        int r = c / 96, cc = c % 96;
        *(uint4*)&wd_s[r][cc * 4] = *(const uint4*)(wdb + ((size_t)(b * T_ + r)) * H_ + cc * 8);
    }
    if (threadIdx.x < 192) *(float4*)&v_s[threadIdx.x * 4] = ((const float4*)V)[threadIdx.x];
    __syncthreads();

    const int t = threadIdx.x >> 4;
    const int ls = threadIdx.x & 15;
    const int l = l0 + ls;
    const int X = Xi[b * T_ + t];
    if (!__any(l >= X)) return;

    float a0 = 0.f, a1 = 0.f, a2 = 0.f, a3 = 0.f;
#pragma unroll 4
    for (int h = 0; h < H_; h += 8) {
        float4 w0 = *(const float4*)&we_s[ls][h];
        float4 w1 = *(const float4*)&we_s[ls][h + 4];
        uint4  wd = *(const uint4*)&wd_s[t][h >> 1];
        float4 v0 = *(const float4*)&v_s[h];
        float4 v1 = *(const float4*)&v_s[h + 4];
        a0 = fmaf(selu_core(w0.x + bf_lo(wd.x)), v0.x, a0);
        a1 = fmaf(selu_core(w0.y + bf_hi(wd.x)), v0.y, a1);
        a2 = fmaf(selu_core(w0.z + bf_lo(wd.y)), v0.z, a2);
        a3 = fmaf(selu_core(w0.w + bf_hi(wd.y)), v0.w, a3);
        a0 = fmaf(selu_core(w1.x + bf_lo(wd.z)), v1.x, a0);
        a1 = fmaf(selu_core(w1.y + bf_hi(wd.z)), v1.y, a1);
        a2 = fmaf(selu_core(w1.z + bf_lo(wd.w)), v1.z, a2);
        a3 = fmaf(selu_core(w1.w + bf_hi(wd.w)), v1.w, a3);
    }
    float dot = SELU_SCALE * ((a0 + a1) + (a2 + a3));
    float sc  = dot > 0.0f ? SELU_SCALE * dot
                           : SELU_SCALE * SELU_ALPHA * (__expf(dot) - 1.0f);
    scores[((size_t)(b * T_ + t)) * L_ + l] = sc;
}

// ---------------- per-(b,t) masked logsumexp + gold + mean (atomic) -------------
__global__ __launch_bounds__(64) void loss_k(
        const float* __restrict__ scores, const int* __restrict__ Xi,
        const int* __restrict__ Yi, float* __restrict__ out) {
    const int bt = blockIdx.x;
    const int lane = threadIdx.x;
    const int X = Xi[bt];
    const int Y = Yi[bt];
    const float* row = scores + (size_t)bt * L_;

    float m = -INFINITY;
    for (int l = X + lane; l < L_; l += 64) m = fmaxf(m, row[l]);
#pragma unroll
    for (int off = 32; off > 0; off >>= 1) m = fmaxf(m, __shfl_xor(m, off));

    float s = 0.0f;
    for (int l = X + lane; l < L_; l += 64) s += __expf(row[l] - m);
#pragma unroll
    for (int off = 32; off > 0; off >>= 1) s += __shfl_xor(s, off);

    if (lane == 0)
        atomicAdd(out, (m + __logf(s) - row[Y]) * (1.0f / (B_ * T_)));
}

// ---------------- launch ----------------
extern "C" void kernel_launch(void* const* d_in, const int* in_sizes, int n_in,
                              void* d_out, int out_size, void* d_ws, size_t ws_size,
                              hipStream_t stream) {
    const float* hn  = (const float*)d_in[0];
    const float* dec = (const float*)d_in[1];
    const float* W1  = (const float*)d_in[2];
    const float* W2  = (const float*)d_in[3];
    const float* V   = (const float*)d_in[4];
    const int*   Xi  = (const int*)d_in[5];
    const int*   Yi  = (const int*)d_in[6];
    float* out = (float*)d_out;

    char* ws = (char*)d_ws;
    size_t off = 0;
    auto alloc = [&](size_t bytes) -> char* {
        char* p = ws + off;
        off += (bytes + 255) & ~(size_t)255;
        return p;
    };
    __bf16* w1b    = (__bf16*)alloc((size_t)H_ * H_ * 2);
    __bf16* w2b    = (__bf16*)alloc((size_t)H_ * H_ * 2);
    float*  djf    = (float*)alloc((size_t)B_ * T_ * H_ * 4);
    __bf16* web    = (__bf16*)alloc((size_t)B_ * L_ * H_ * 2);
    __bf16* wdb    = (__bf16*)alloc((size_t)B_ * T_ * H_ * 2);
    float*  scores = (float*)alloc((size_t)B_ * T_ * L_ * 4);

    // prep: (2*147456 + 49152) / 256 = 1344 blocks
    prep_k<<<1344, 256, 0, stream>>>(W1, W2, dec, Yi, w1b, w2b, djf, out);
    // WE (768 blocks, XCD-swizzled) + WD (24 blocks), static prefetch-2 pipeline
    gemm_k<<<792, 256, 0, stream>>>(hn, djf, w1b, w2b, web, wdb);
    scores_k<<<dim3(B_, L_ / 16), 256, 0, stream>>>(web, wdb, V, Xi, scores);
    loss_k<<<B_ * T_, 64, 0, stream>>>(scores, Xi, Yi, out);
}

// Round 9
// 156.953 us; speedup vs baseline: 1.2158x; 1.0108x over previous
//
#include <hip/hip_runtime.h>
#include <hip/hip_bf16.h>
#include <math.h>

#define SELU_SCALE 1.0507009873554805f
#define SELU_ALPHA 1.6732632423543772f

static constexpr int B_ = 16, T_ = 16, L_ = 512, H_ = 768;

typedef __bf16 bf16x8 __attribute__((ext_vector_type(8)));
typedef __bf16 bf16x4 __attribute__((ext_vector_type(4)));
typedef float  f32x4  __attribute__((ext_vector_type(4)));

__device__ __forceinline__ float bf_lo(unsigned u) { return __uint_as_float(u << 16); }
__device__ __forceinline__ float bf_hi(unsigned u) { return __uint_as_float(u & 0xFFFF0000u); }

__device__ __forceinline__ float selu_core(float x) {
    float e = fmaf(__expf(x), SELU_ALPHA, -SELU_ALPHA);
    return x > 0.0f ? x : e;
}

__device__ __forceinline__ bf16x4 cvt4(float4 f) {
    bf16x4 o;
    o.x = (__bf16)f.x; o.y = (__bf16)f.y; o.z = (__bf16)f.z; o.w = (__bf16)f.w;
    return o;
}

// LDS k-segment slot swizzle: slot = seg ^ ((row>>1)&3) -- conflict-free for all
// ds_write_b128 / ds_read_b128 patterns in gemm_k (r6 measured 0 conflicts).
__device__ __forceinline__ int xsw(int r) { return (r >> 1) & 3; }

// ---------------- prep: W1/W2 -> bf16, dj gather (f32), zero out ----------------
__global__ __launch_bounds__(256) void prep_k(
        const float* __restrict__ w1, const float* __restrict__ w2,
        const float* __restrict__ dec, const int* __restrict__ Yi,
        __bf16* __restrict__ w1b, __bf16* __restrict__ w2b,
        float* __restrict__ djf, float* __restrict__ out) {
    const int NW = H_ * H_ / 4;                // 147456 float4s
    int i = blockIdx.x * 256 + threadIdx.x;
    if (i == 0) out[0] = 0.0f;
    if (i < NW) {
        ((bf16x4*)w1b)[i] = cvt4(((const float4*)w1)[i]);
    } else if (i < 2 * NW) {
        int j = i - NW;
        ((bf16x4*)w2b)[j] = cvt4(((const float4*)w2)[j]);
    } else {
        int j = i - 2 * NW;                    // < 49152
        int bt = j / 192, c = j % 192;
        int b = bt >> 4;
        int y = Yi[bt];
        ((float4*)djf)[bt * 192 + c] = ((const float4*)dec)[(b * L_ + y) * 192 + c];
    }
}

// ---------------- register-pipelined NT GEMM (WE + WD), 8 waves ----------------
// C[m][n] = sum_k A[m][k]*B[n][k]. A f32 (convert in-register), B bf16.
// BM=64, BN=128, BK=32 as r8, but 512 threads = 8 waves of 32x32 wave-tiles
// (2x4 grid) -> ~24 resident waves/CU (vs 12) to hide VMEM/LDS/barrier latency.
// XCD-aware mapping (same-m blocks stride 128 == 0 mod 8 -> same XCD L2).
// Prefetch distance 2, statically named ping/pong register sets.
__global__ __launch_bounds__(512) void gemm_k(
        const float* __restrict__ hn, const float* __restrict__ djf,
        const __bf16* __restrict__ w1b, const __bf16* __restrict__ w2b,
        __bf16* __restrict__ web, __bf16* __restrict__ wdb) {
    __shared__ __bf16 As[64 * 32];    // 4 KB
    __shared__ __bf16 Bs[128 * 32];   // 8 KB

    int bx = blockIdx.x;
    const float* Af; const __bf16* Bw; __bf16* C; int m0, n0;
    if (bx < 768) {                       // WE: 128 m-tiles x 6 n-chunks
        Af = hn;  Bw = w1b; C = web;
        m0 = (bx & 127) * 64; n0 = (bx >> 7) * 128;
    } else {                              // WD: 4 m-tiles x 6 n-chunks
        bx -= 768;
        Af = djf; Bw = w2b; C = wdb;
        m0 = (bx & 3) * 64;   n0 = (bx >> 2) * 128;
    }

    const int tid = threadIdx.x;
    const int wave = tid >> 6, lane = tid & 63;
    const int wm = (wave >> 2) * 32, wn = (wave & 3) * 32;
    const int lr = lane & 15, q = lane >> 4;

    // A staging: threads 0..255 -> row (tid&255)>>2, k-seg tid&3 (8 f32 -> b128)
    const bool doA = (tid < 256);
    const int arow = (tid & 255) >> 2, aseg = tid & 3;
    const float* Ag = Af + (size_t)(m0 + arow) * 768 + aseg * 8;
    bf16x8* AsW = (bf16x8*)&As[arow * 32 + ((aseg ^ xsw(arow)) * 8)];

    // B staging: all 512 threads -> row tid>>2 (0..127), k-seg tid&3 (1 b128)
    const int brow = tid >> 2, bseg = tid & 3;
    const __bf16* Bg = Bw + (size_t)(n0 + brow) * 768 + bseg * 8;
    uint4* BsW = (uint4*)&Bs[brow * 32 + ((bseg ^ xsw(brow)) * 8)];

    // fragment read offsets (seg q of row)
    int aoff[2], boff[2];
#pragma unroll
    for (int i = 0; i < 2; ++i) {
        int r = wm + i * 16 + lr;
        aoff[i] = r * 32 + (q ^ xsw(r)) * 8;
    }
#pragma unroll
    for (int j = 0; j < 2; ++j) {
        int r = wn + j * 16 + lr;
        boff[j] = r * 32 + (q ^ xsw(r)) * 8;
    }

    f32x4 acc[2][2] = {};

    // prologue: tile 0 -> set X, tile 1 -> set Y (statically named)
    float4 pax0{}, pax1{}, pay0{}, pay1{};
    if (doA) {
        pax0 = *(const float4*)(Ag);      pax1 = *(const float4*)(Ag + 4);
        pay0 = *(const float4*)(Ag + 32); pay1 = *(const float4*)(Ag + 36);
    }
    uint4 pbx = *(const uint4*)(Bg);
    uint4 pby = *(const uint4*)(Bg + 32);

#pragma unroll 1
    for (int k0 = 0; k0 < 768; k0 += 64) {
        // ======== sub-iter X: tile k0 ========
        {
            if (doA) {
                bf16x8 aw;
                aw[0] = (__bf16)pax0.x; aw[1] = (__bf16)pax0.y;
                aw[2] = (__bf16)pax0.z; aw[3] = (__bf16)pax0.w;
                aw[4] = (__bf16)pax1.x; aw[5] = (__bf16)pax1.y;
                aw[6] = (__bf16)pax1.z; aw[7] = (__bf16)pax1.w;
                *AsW = aw;
            }
            *BsW = pbx;
            asm volatile("s_waitcnt lgkmcnt(0)\n\ts_barrier" ::: "memory");
            if (k0 + 64 < 768) {   // prefetch tile k0+64 into set X
                if (doA) {
                    pax0 = *(const float4*)(Ag + k0 + 64);
                    pax1 = *(const float4*)(Ag + k0 + 68);
                }
                pbx = *(const uint4*)(Bg + k0 + 64);
            }
            bf16x8 af[2], bfr[2];
#pragma unroll
            for (int i = 0; i < 2; ++i) af[i]  = *(const bf16x8*)&As[aoff[i]];
#pragma unroll
            for (int j = 0; j < 2; ++j) bfr[j] = *(const bf16x8*)&Bs[boff[j]];
#pragma unroll
            for (int i = 0; i < 2; ++i)
#pragma unroll
                for (int j = 0; j < 2; ++j)
                    acc[i][j] = __builtin_amdgcn_mfma_f32_16x16x32_bf16(af[i], bfr[j], acc[i][j], 0, 0, 0);
            asm volatile("s_barrier" ::: "memory");
        }
        // ======== sub-iter Y: tile k0+32 ========
        {
            if (doA) {
                bf16x8 aw;
                aw[0] = (__bf16)pay0.x; aw[1] = (__bf16)pay0.y;
                aw[2] = (__bf16)pay0.z; aw[3] = (__bf16)pay0.w;
                aw[4] = (__bf16)pay1.x; aw[5] = (__bf16)pay1.y;
                aw[6] = (__bf16)pay1.z; aw[7] = (__bf16)pay1.w;
                *AsW = aw;
            }
            *BsW = pby;
            asm volatile("s_waitcnt lgkmcnt(0)\n\ts_barrier" ::: "memory");
            if (k0 + 96 < 768) {   // prefetch tile k0+96 into set Y
                if (doA) {
                    pay0 = *(const float4*)(Ag + k0 + 96);
                    pay1 = *(const float4*)(Ag + k0 + 100);
                }
                pby = *(const uint4*)(Bg + k0 + 96);
            }
            bf16x8 af[2], bfr[2];
#pragma unroll
            for (int i = 0; i < 2; ++i) af[i]  = *(const bf16x8*)&As[aoff[i]];
#pragma unroll
            for (int j = 0; j < 2; ++j) bfr[j] = *(const bf16x8*)&Bs[boff[j]];
#pragma unroll
            for (int i = 0; i < 2; ++i)
#pragma unroll
                for (int j = 0; j < 2; ++j)
                    acc[i][j] = __builtin_amdgcn_mfma_f32_16x16x32_bf16(af[i], bfr[j], acc[i][j], 0, 0, 0);
            asm volatile("s_barrier" ::: "memory");
        }
    }

#pragma unroll
    for (int i = 0; i < 2; ++i)
#pragma unroll
        for (int j = 0; j < 2; ++j)
#pragma unroll
            for (int r = 0; r < 4; ++r) {
                int row = m0 + wm + i * 16 + q * 4 + r;
                int col = n0 + wn + j * 16 + lr;
                C[(size_t)row * 768 + col] = (__bf16)acc[i][j][r];
            }
}

// ---------------- fused scores: per-lane (t,l), no shuffles ----------------
__global__ __launch_bounds__(256) void scores_k(
        const __bf16* __restrict__ web, const __bf16* __restrict__ wdb,
        const float* __restrict__ V, const int* __restrict__ Xi,
        float* __restrict__ scores) {
    __shared__ float    we_s[16][772];
    __shared__ unsigned wd_s[16][388];
    __shared__ float    v_s[768];

    const int b = blockIdx.x, l0 = blockIdx.y * 16;

    for (int c = threadIdx.x; c < 16 * 96; c += 256) {
        int r = c / 96, cc = c % 96;
        uint4 v = *(const uint4*)(web + ((size_t)(b * L_ + l0 + r)) * H_ + cc * 8);
        float4 f0, f1;
        f0.x = bf_lo(v.x); f0.y = bf_hi(v.x); f0.z = bf_lo(v.y); f0.w = bf_hi(v.y);
        f1.x = bf_lo(v.z); f1.y = bf_hi(v.z); f1.z = bf_lo(v.w); f1.w = bf_hi(v.w);
        *(float4*)&we_s[r][cc * 8]     = f0;
        *(float4*)&we_s[r][cc * 8 + 4] = f1;
    }
    for (int c = threadIdx.x; c < 16 * 96; c += 256) {
        int r = c / 96, cc = c % 96;
        *(uint4*)&wd_s[r][cc * 4] = *(const uint4*)(wdb + ((size_t)(b * T_ + r)) * H_ + cc * 8);
    }
    if (threadIdx.x < 192) *(float4*)&v_s[threadIdx.x * 4] = ((const float4*)V)[threadIdx.x];
    __syncthreads();

    const int t = threadIdx.x >> 4;
    const int ls = threadIdx.x & 15;
    const int l = l0 + ls;
    const int X = Xi[b * T_ + t];
    if (!__any(l >= X)) return;

    float a0 = 0.f, a1 = 0.f, a2 = 0.f, a3 = 0.f;
#pragma unroll 4
    for (int h = 0; h < H_; h += 8) {
        float4 w0 = *(const float4*)&we_s[ls][h];
        float4 w1 = *(const float4*)&we_s[ls][h + 4];
        uint4  wd = *(const uint4*)&wd_s[t][h >> 1];
        float4 v0 = *(const float4*)&v_s[h];
        float4 v1 = *(const float4*)&v_s[h + 4];
        a0 = fmaf(selu_core(w0.x + bf_lo(wd.x)), v0.x, a0);
        a1 = fmaf(selu_core(w0.y + bf_hi(wd.x)), v0.y, a1);
        a2 = fmaf(selu_core(w0.z + bf_lo(wd.y)), v0.z, a2);
        a3 = fmaf(selu_core(w0.w + bf_hi(wd.y)), v0.w, a3);
        a0 = fmaf(selu_core(w1.x + bf_lo(wd.z)), v1.x, a0);
        a1 = fmaf(selu_core(w1.y + bf_hi(wd.z)), v1.y, a1);
        a2 = fmaf(selu_core(w1.z + bf_lo(wd.w)), v1.z, a2);
        a3 = fmaf(selu_core(w1.w + bf_hi(wd.w)), v1.w, a3);
    }
    float dot = SELU_SCALE * ((a0 + a1) + (a2 + a3));
    float sc  = dot > 0.0f ? SELU_SCALE * dot
                           : SELU_SCALE * SELU_ALPHA * (__expf(dot) - 1.0f);
    scores[((size_t)(b * T_ + t)) * L_ + l] = sc;
}

// ---------------- per-(b,t) masked logsumexp + gold + mean (atomic) -------------
__global__ __launch_bounds__(64) void loss_k(
        const float* __restrict__ scores, const int* __restrict__ Xi,
        const int* __restrict__ Yi, float* __restrict__ out) {
    const int bt = blockIdx.x;
    const int lane = threadIdx.x;
    const int X = Xi[bt];
    const int Y = Yi[bt];
    const float* row = scores + (size_t)bt * L_;

    float m = -INFINITY;
    for (int l = X + lane; l < L_; l += 64) m = fmaxf(m, row[l]);
#pragma unroll
    for (int off = 32; off > 0; off >>= 1) m = fmaxf(m, __shfl_xor(m, off));

    float s = 0.0f;
    for (int l = X + lane; l < L_; l += 64) s += __expf(row[l] - m);
#pragma unroll
    for (int off = 32; off > 0; off >>= 1) s += __shfl_xor(s, off);

    if (lane == 0)
        atomicAdd(out, (m + __logf(s) - row[Y]) * (1.0f / (B_ * T_)));
}

// ---------------- launch ----------------
extern "C" void kernel_launch(void* const* d_in, const int* in_sizes, int n_in,
                              void* d_out, int out_size, void* d_ws, size_t ws_size,
                              hipStream_t stream) {
    const float* hn  = (const float*)d_in[0];
    const float* dec = (const float*)d_in[1];
    const float* W1  = (const float*)d_in[2];
    const float* W2  = (const float*)d_in[3];
    const float* V   = (const float*)d_in[4];
    const int*   Xi  = (const int*)d_in[5];
    const int*   Yi  = (const int*)d_in[6];
    float* out = (float*)d_out;

    char* ws = (char*)d_ws;
    size_t off = 0;
    auto alloc = [&](size_t bytes) -> char* {
        char* p = ws + off;
        off += (bytes + 255) & ~(size_t)255;
        return p;
    };
    __bf16* w1b    = (__bf16*)alloc((size_t)H_ * H_ * 2);
    __bf16* w2b    = (__bf16*)alloc((size_t)H_ * H_ * 2);
    float*  djf    = (float*)alloc((size_t)B_ * T_ * H_ * 4);
    __bf16* web    = (__bf16*)alloc((size_t)B_ * L_ * H_ * 2);
    __bf16* wdb    = (__bf16*)alloc((size_t)B_ * T_ * H_ * 2);
    float*  scores = (float*)alloc((size_t)B_ * T_ * L_ * 4);

    // prep: (2*147456 + 49152) / 256 = 1344 blocks
    prep_k<<<1344, 256, 0, stream>>>(W1, W2, dec, Yi, w1b, w2b, djf, out);
    // WE (768 blocks, XCD-swizzled) + WD (24 blocks), 8 waves, prefetch-2
    gemm_k<<<792, 512, 0, stream>>>(hn, djf, w1b, w2b, web, wdb);
    scores_k<<<dim3(B_, L_ / 16), 256, 0, stream>>>(web, wdb, V, Xi, scores);
    loss_k<<<B_ * T_, 64, 0, stream>>>(scores, Xi, Yi, out);
}